// Round 9
// baseline (168.867 us; speedup 1.0000x reference)
//
#include <hip/hip_runtime.h>

#define BB 8
#define LL 2048
#define DD 256

typedef _Float16 half8 __attribute__((ext_vector_type(8)));
typedef float floatx4 __attribute__((ext_vector_type(4)));
typedef unsigned short ushort8 __attribute__((ext_vector_type(8)));

__device__ inline unsigned short f2h(float f) {
  _Float16 h = (_Float16)f;
  return __builtin_bit_cast(unsigned short, h);
}

// ---------------------------------------------------------------------------
// Kernel 1: fused W-convert + QKV projection.  grid 256 (64-row tiles,
// 1 block/CU), block 512 (8 waves).
// Per group g (12 = 3 mats x 4 o-groups of 64):
//   [A] barrier; ds_write W f16 (reg-staged, swizzled cc^(row&7))
//   [B] barrier; issue W f32 loads for g+1 (pinned, overlap MFMA)
//       MFMA: wave w -> ot=w>>1 (o-tile), p=w&1 (row-half);
//             acc[j] over mt=p*2+j; writes LDS out-tile
//   og==3: [C] barrier; coalesced flush of the mat's tile
// LDS: Ws 32KB + tile 36.9KB = 69.6KB.
// ---------------------------------------------------------------------------
__global__ __launch_bounds__(512) void proj(
    const float* __restrict__ x, const float* __restrict__ Wq,
    const float* __restrict__ Wk, const float* __restrict__ Wv,
    unsigned short* __restrict__ Qb, unsigned short* __restrict__ Kb,
    unsigned short* __restrict__ VT) {
  // [0,32768)      Ws: 64 rows x 256 f16, chunk cc stored at cc^(row&7)
  // [32768,69632)  tile: Q/K 64 x 264 f16 (l-major) | VT 256 x 72 (o-major)
  __shared__ __attribute__((aligned(16))) unsigned char smem[69632];
  unsigned short* Ws = (unsigned short*)smem;
  unsigned short* tile = (unsigned short*)(smem + 32768);
  const int t = threadIdx.x;
  const int wave = t >> 6, lane = t & 63, quad = lane >> 4, m16 = lane & 15;
  const int ot = wave >> 1, p = wave & 1;  // o-tile, row-half
  const int l0g = blockIdx.x * 64;
  const int b = l0g >> 11, lb = l0g & 2047;

  // x A-frags for this wave's 2 m-tiles (rows p*32 .. p*32+31)
  half8 xf[2][8];
#pragma unroll
  for (int j = 0; j < 2; ++j) {
    const float* xp =
        x + (size_t)(l0g + (p * 2 + j) * 16 + m16) * DD + quad * 8;
#pragma unroll
    for (int kb = 0; kb < 8; ++kb) {
      float4 a = *(const float4*)(xp + kb * 32);
      float4 c = *(const float4*)(xp + kb * 32 + 4);
      ushort8 u = {f2h(a.x), f2h(a.y), f2h(a.z), f2h(a.w),
                   f2h(c.x), f2h(c.y), f2h(c.z), f2h(c.w)};
      xf[j][kb] = __builtin_bit_cast(half8, u);
    }
  }

  // W reg double-buffer: 4 chunks/thread (ch = c*512 + t), 8 f32 each.
  float4 wA[4], wB[4];
#define LOADW(G)                                                              \
  {                                                                           \
    const int mat_ = (G) >> 2, og_ = (G)&3;                                   \
    const float* Wm = (mat_ == 0) ? Wq : (mat_ == 1) ? Wk : Wv;               \
    _Pragma("unroll") for (int c = 0; c < 4; ++c) {                           \
      int ch = c * 512 + t, row = ch >> 5, cc = ch & 31;                      \
      const float* s = Wm + (size_t)(og_ * 64 + row) * DD + cc * 8;           \
      wA[c] = *(const float4*)s;                                              \
      wB[c] = *(const float4*)(s + 4);                                        \
    }                                                                         \
  }

  LOADW(0);
  asm volatile("" ::: "memory");

  for (int g = 0; g < 12; ++g) {
    const int mat = g >> 2, og = g & 3;
    __syncthreads();  // [A] Ws readers (g-1) + flush readers done
#pragma unroll
    for (int c = 0; c < 4; ++c) {
      int ch = c * 512 + t, row = ch >> 5, cc = ch & 31;
      ushort8 u = {f2h(wA[c].x), f2h(wA[c].y), f2h(wA[c].z), f2h(wA[c].w),
                   f2h(wB[c].x), f2h(wB[c].y), f2h(wB[c].z), f2h(wB[c].w)};
      *(ushort8*)&Ws[row * 256 + ((cc ^ (row & 7)) << 3)] = u;
    }
    __syncthreads();  // [B] Ws visible
    if (g < 11) {
      LOADW(g + 1);   // overlaps MFMA phase
      asm volatile("" ::: "memory");
    }

    floatx4 acc[2] = {{0, 0, 0, 0}, {0, 0, 0, 0}};
    if (mat < 2) {
#pragma unroll
      for (int kb = 0; kb < 8; ++kb) {
        half8 wf = __builtin_bit_cast(
            half8, *(const ushort8*)&Ws[(ot * 16 + m16) * 256 +
                                        (((kb * 4 + quad) ^ (m16 & 7)) << 3)]);
        acc[0] = __builtin_amdgcn_mfma_f32_16x16x32_f16(xf[0][kb], wf,
                                                        acc[0], 0, 0, 0);
        acc[1] = __builtin_amdgcn_mfma_f32_16x16x32_f16(xf[1][kb], wf,
                                                        acc[1], 0, 0, 0);
      }
      // D: row=l, col=o -> tile l-major [64][264]
#pragma unroll
      for (int j = 0; j < 2; ++j)
#pragma unroll
        for (int r = 0; r < 4; ++r)
          tile[((p * 2 + j) * 16 + quad * 4 + r) * 264 + og * 64 + ot * 16 +
               m16] = f2h(acc[j][r]);
    } else {
#pragma unroll
      for (int kb = 0; kb < 8; ++kb) {
        half8 wf = __builtin_bit_cast(
            half8, *(const ushort8*)&Ws[(ot * 16 + m16) * 256 +
                                        (((kb * 4 + quad) ^ (m16 & 7)) << 3)]);
        acc[0] = __builtin_amdgcn_mfma_f32_16x16x32_f16(wf, xf[0][kb],
                                                        acc[0], 0, 0, 0);
        acc[1] = __builtin_amdgcn_mfma_f32_16x16x32_f16(wf, xf[1][kb],
                                                        acc[1], 0, 0, 0);
      }
      // swapped: row=o, col=l -> tile o-major [256][72]
#pragma unroll
      for (int j = 0; j < 2; ++j)
#pragma unroll
        for (int r = 0; r < 4; ++r)
          tile[(og * 64 + ot * 16 + quad * 4 + r) * 72 + (p * 2 + j) * 16 +
               m16] = f2h(acc[j][r]);
    }

    if (og == 3) {
      __syncthreads();  // [C] all tile writes of this mat done
      if (mat < 2) {
        unsigned short* Out = mat ? Kb : Qb;
        const int row = t >> 3, c0 = (t & 7) * 8;  // 64 rows x 256 o
#pragma unroll
        for (int i = 0; i < 4; ++i) {
          ushort8 v = *(const ushort8*)&tile[row * 264 + c0 + i * 64];
          *(ushort8*)(Out + (size_t)(l0g + row) * DD + c0 + i * 64) = v;
        }
      } else {
#pragma unroll
        for (int c = 0; c < 4; ++c) {
          int ch = c * 512 + t, d = ch >> 3, lc = (ch & 7) * 8;  // 256d x 64l
          ushort8 v = *(const ushort8*)&tile[d * 72 + lc];
          *(ushort8*)(VT + ((size_t)(b * DD + d)) * LL + lb + lc) = v;
        }
      }
      // flush readers protected by next group's [A] barrier
    }
  }
#undef LOADW
}

// ---------------------------------------------------------------------------
// Kernel 2: flash attention — byte-identical to round 7 (81.6 us).
// ---------------------------------------------------------------------------
__global__ __launch_bounds__(512, 1) void attn(
    const unsigned short* __restrict__ Qb, const unsigned short* __restrict__ Kb,
    const unsigned short* __restrict__ VT, const int* __restrict__ lens,
    float* __restrict__ out) {
  // [0,65536): Ks (2 grp x 64x256)  [65536,131072): Vs (2 grp x 256x64)
  // [131072,149504): Ps (8 waves x 16x72)
  __shared__ __attribute__((aligned(16))) unsigned char smem[149504];
  const int t = threadIdx.x;
  const int wave = t >> 6, lane = t & 63, quad = lane >> 4, m16 = lane & 15;
  const int grp = wave >> 2, qw = wave & 3, tgl = t & 255;
  unsigned short* Ks = (unsigned short*)(smem + grp * 32768);
  unsigned short* Vs = (unsigned short*)(smem + 65536 + grp * 32768);
  unsigned short* Pw = (unsigned short*)(smem + 131072 + wave * 2304);

  const int b = blockIdx.x;           // batch on x -> XCD affinity
  const int q0 = blockIdx.y * 64;
  const int len = lens[b];
  const size_t baseQK = (size_t)b * LL * DD;
  const size_t baseVT = (size_t)b * DD * LL;

  half8 qf[8];
  {
    const unsigned short* qrow =
        Qb + baseQK + (size_t)(q0 + qw * 16 + m16) * DD + quad * 8;
    for (int kb = 0; kb < 8; ++kb)
      qf[kb] = __builtin_bit_cast(half8, *(const ushort8*)(qrow + kb * 32));
  }

  floatx4 O[16];
  for (int i = 0; i < 16; ++i) O[i] = (floatx4){0, 0, 0, 0};
  float mrow[4] = {-1e30f, -1e30f, -1e30f, -1e30f};
  float lrow[4] = {0.f, 0.f, 0.f, 0.f};

  ushort8 kreg[8], vreg[8];
  const unsigned short* kbase = Kb + baseQK;
  const unsigned short* vbase = VT + baseVT;

#define LOAD_TILES(KV0)                                                      \
  {                                                                          \
    const unsigned short* kp = kbase + (size_t)(KV0)*DD;                     \
    for (int c = 0; c < 8; ++c)                                              \
      kreg[c] = *(const ushort8*)(kp + (tgl + c * 256) * 8);                 \
    for (int c = 0; c < 8; ++c) {                                            \
      int ch = tgl + c * 256;                                                \
      vreg[c] = *(const ushort8*)(vbase + (size_t)(ch >> 3) * LL + (KV0) +   \
                                  (ch & 7) * 8);                             \
    }                                                                        \
  }

  const int T = (len + 127) >> 7;  // uniform trip count, 128 kv per iter
  LOAD_TILES(grp * 64);
  asm volatile("" ::: "memory");  // pin prefetch issue point

  for (int it = 0; it < T; ++it) {
    const int kv0 = it * 128 + grp * 64;
    __syncthreads();
    for (int c = 0; c < 8; ++c) {
      int ch = tgl + c * 256, row = ch >> 5, cc = ch & 31;
      *(ushort8*)&Ks[row * 256 + (cc ^ (row & 7)) * 8] = kreg[c];
    }
    for (int c = 0; c < 8; ++c) {
      int ch = tgl + c * 256, d = ch >> 3, cc = ch & 7;
      *(ushort8*)&Vs[d * 64 + (cc ^ (d & 7)) * 8] = vreg[c];
    }
    __syncthreads();
    if (it + 1 < T) {
      LOAD_TILES(kv0 + 128);
      asm volatile("" ::: "memory");  // keep loads issued here, results live
    }

    if (kv0 < len) {
      // S = Q K^T
      floatx4 s[4];
      for (int n = 0; n < 4; ++n) s[n] = (floatx4){0, 0, 0, 0};
      __builtin_amdgcn_s_setprio(1);
      for (int kb = 0; kb < 8; ++kb)
        for (int n = 0; n < 4; ++n) {
          half8 kf = __builtin_bit_cast(
              half8, *(const ushort8*)&Ks[(n * 16 + m16) * 256 +
                                          (((kb * 4 + quad) ^ (m16 & 7)) * 8)]);
          s[n] = __builtin_amdgcn_mfma_f32_16x16x32_f16(qf[kb], kf, s[n], 0, 0, 0);
        }
      __builtin_amdgcn_s_setprio(0);
      float sv[4][4];
      for (int n = 0; n < 4; ++n) {
        bool valid = (kv0 + n * 16 + m16) < len;
        for (int r = 0; r < 4; ++r)
          sv[n][r] = valid ? s[n][r] * 0.0625f : -1e30f;
      }
      float al[4];
      for (int r = 0; r < 4; ++r) {
        float v = fmaxf(fmaxf(sv[0][r], sv[1][r]), fmaxf(sv[2][r], sv[3][r]));
        v = fmaxf(v, __shfl_xor(v, 1));
        v = fmaxf(v, __shfl_xor(v, 2));
        v = fmaxf(v, __shfl_xor(v, 4));
        v = fmaxf(v, __shfl_xor(v, 8));
        float mn = fmaxf(mrow[r], v);
        al[r] = __expf(mrow[r] - mn);
        mrow[r] = mn;
        float sum = 0.f;
        for (int n = 0; n < 4; ++n) {
          float p = __expf(sv[n][r] - mn);
          Pw[(quad * 4 + r) * 72 + n * 16 + m16] = f2h(p);
          sum += p;
        }
        sum += __shfl_xor(sum, 1);
        sum += __shfl_xor(sum, 2);
        sum += __shfl_xor(sum, 4);
        sum += __shfl_xor(sum, 8);
        lrow[r] = lrow[r] * al[r] + sum;
      }
      for (int i = 0; i < 16; ++i)
        for (int r = 0; r < 4; ++r) O[i][r] *= al[r];
      half8 pf0 = __builtin_bit_cast(half8,
                                     *(const ushort8*)&Pw[m16 * 72 + quad * 8]);
      half8 pf1 = __builtin_bit_cast(
          half8, *(const ushort8*)&Pw[m16 * 72 + 32 + quad * 8]);
      __builtin_amdgcn_s_setprio(1);
      for (int nb = 0; nb < 16; ++nb) {
        half8 vf0 = __builtin_bit_cast(
            half8, *(const ushort8*)&Vs[(nb * 16 + m16) * 64 +
                                        ((quad ^ (m16 & 7)) * 8)]);
        O[nb] = __builtin_amdgcn_mfma_f32_16x16x32_f16(pf0, vf0, O[nb], 0, 0, 0);
        half8 vf1 = __builtin_bit_cast(
            half8, *(const ushort8*)&Vs[(nb * 16 + m16) * 64 +
                                        (((4 + quad) ^ (m16 & 7)) * 8)]);
        O[nb] = __builtin_amdgcn_mfma_f32_16x16x32_f16(pf1, vf1, O[nb], 0, 0, 0);
      }
      __builtin_amdgcn_s_setprio(0);
    }
  }
#undef LOAD_TILES

  // ---- merge group 1 into group 0 via LDS (aliases Ks/Vs region) ----
  __syncthreads();
  float* Om = (float*)(smem) + qw * 4112;       // 16 rows x 257 f32 per wave
  float* ml = (float*)(smem + 65792) + qw * 32; // [2][16] per wave
  if (grp == 1) {
    for (int nb = 0; nb < 16; ++nb)
      for (int r = 0; r < 4; ++r)
        Om[(quad * 4 + r) * 257 + nb * 16 + m16] = O[nb][r];
    if (m16 == 0)
      for (int r = 0; r < 4; ++r) {
        ml[(quad * 4 + r) * 2] = mrow[r];
        ml[(quad * 4 + r) * 2 + 1] = lrow[r];
      }
  }
  __syncthreads();
  if (grp == 0) {
    float a[4], bf[4], inv[4];
    for (int r = 0; r < 4; ++r) {
      float mB = ml[(quad * 4 + r) * 2];
      float lB = ml[(quad * 4 + r) * 2 + 1];
      float m = fmaxf(mrow[r], mB);
      a[r] = __expf(mrow[r] - m);
      bf[r] = __expf(mB - m);
      inv[r] = 1.f / (lrow[r] * a[r] + lB * bf[r]);
    }
    for (int nb = 0; nb < 16; ++nb)
      for (int r = 0; r < 4; ++r) {
        float ob = Om[(quad * 4 + r) * 257 + nb * 16 + m16];
        out[baseQK + (size_t)(q0 + qw * 16 + quad * 4 + r) * DD + nb * 16 +
            m16] = (O[nb][r] * a[r] + ob * bf[r]) * inv[r];
      }
  }
}

extern "C" void kernel_launch(void* const* d_in, const int* in_sizes, int n_in,
                              void* d_out, int out_size, void* d_ws, size_t ws_size,
                              hipStream_t stream) {
  const float* x = (const float*)d_in[0];
  const float* Wq = (const float*)d_in[1];
  const float* Wk = (const float*)d_in[2];
  const float* Wv = (const float*)d_in[3];
  const int* lens = (const int*)d_in[4];
  unsigned short* Qb = (unsigned short*)d_ws;
  unsigned short* Kb = Qb + (size_t)BB * LL * DD;
  unsigned short* VT = Kb + (size_t)BB * LL * DD;
  float* out = (float*)d_out;

  proj<<<256, 512, 0, stream>>>(x, Wq, Wk, Wv, Qb, Kb, VT);
  attn<<<dim3(8, 32), 512, 0, stream>>>(Qb, Kb, VT, lens, out);
}